// Round 2
// baseline (2161.858 us; speedup 1.0000x reference)
//
#include <hip/hip_runtime.h>
#include <hip/hip_bf16.h>
#include <math.h>

#define B_ 2
#define L_ 1024
#define DM 1024
#define DIN 2048
#define DS 16
#define DTR 64

__device__ __forceinline__ float sigmoidf_(float x) { return 1.f / (1.f + expf(-x)); }

// C[M,N] = A[M,K] (lda) * Bt[N,K]^T (ldb), EPI==1: softplus(v + bias[n])
template<int EPI>
__global__ __launch_bounds__(256) void gemm_bt(const float* __restrict__ A,
    const float* __restrict__ Bt, float* __restrict__ C,
    const float* __restrict__ bias, int M, int N, int K, int lda, int ldb)
{
    __shared__ __align__(16) float As[16][68];
    __shared__ __align__(16) float Bs[16][68];
    const int tid = threadIdx.x;
    const int tx = tid & 15, ty = tid >> 4;
    const int n0 = blockIdx.x * 64, m0 = blockIdx.y * 64;
    float acc[4][4] = {};
    for (int k0 = 0; k0 < K; k0 += 16) {
#pragma unroll
        for (int l = 0; l < 4; ++l) {
            int idx = tid + l * 256;
            int mm = idx >> 4, kk = idx & 15;
            As[kk][mm] = A[(size_t)(m0 + mm) * lda + k0 + kk];
            float bv = 0.f;
            if (n0 + mm < N) bv = Bt[(size_t)(n0 + mm) * ldb + k0 + kk];
            Bs[kk][mm] = bv;
        }
        __syncthreads();
#pragma unroll
        for (int kk = 0; kk < 16; ++kk) {
            float4 av = *reinterpret_cast<const float4*>(&As[kk][ty * 4]);
            float4 bv = *reinterpret_cast<const float4*>(&Bs[kk][tx * 4]);
            const float a[4] = {av.x, av.y, av.z, av.w};
            const float b[4] = {bv.x, bv.y, bv.z, bv.w};
#pragma unroll
            for (int im = 0; im < 4; ++im)
#pragma unroll
                for (int in = 0; in < 4; ++in)
                    acc[im][in] = fmaf(a[im], b[in], acc[im][in]);
        }
        __syncthreads();
    }
#pragma unroll
    for (int im = 0; im < 4; ++im) {
        int m = m0 + ty * 4 + im;
#pragma unroll
        for (int in = 0; in < 4; ++in) {
            int n = n0 + tx * 4 + in;
            if (n < N) {
                float v = acc[im][in];
                if (EPI == 1) {
                    float s = v + bias[n];
                    v = (s > 20.f) ? s : log1pf(expf(s));
                }
                C[(size_t)m * N + n] = v;
            }
        }
    }
}

// uc[b,t,d] = silu( sum_j cw[d,j]*u[b,t-3+j,d] + cb[d] ), u = xz[...,0:DIN]
__global__ __launch_bounds__(256) void conv_silu_k(const float* __restrict__ xz,
    const float* __restrict__ cw, const float* __restrict__ cb, float* __restrict__ uc)
{
    int idx = blockIdx.x * 256 + threadIdx.x;   // over B*L*DIN
    int d = idx & (DIN - 1);
    int t = (idx >> 11) & (L_ - 1);
    int b = idx >> 21;
    const float* base = xz + (size_t)b * L_ * (2 * DIN) + d;
    float acc = cb[d];
#pragma unroll
    for (int j = 0; j < 4; ++j) {
        int tt = t - 3 + j;
        if (tt >= 0) acc = fmaf(cw[d * 4 + j], base[(size_t)tt * (2 * DIN)], acc);
    }
    uc[idx] = acc * sigmoidf_(acc);
}

// selective scan: 16 lanes per channel (state dim), LDS chunk staging of 64 steps
__global__ __launch_bounds__(256) void scan_k(const float* __restrict__ dtf,
    float* __restrict__ uc, const float* __restrict__ xdbl,
    const float* __restrict__ A_log, const float* __restrict__ Dvec)
{
    __shared__ float sBC[64][32];
    __shared__ float sdt[64][16];
    __shared__ float su[64][16];
    __shared__ float sy[64][16];
    const int tid = threadIdx.x;
    const int g = tid >> 4;     // local channel 0..15
    const int n = tid & 15;     // state index
    const int b = blockIdx.x >> 7;            // 128 blocks per batch
    const int dbase = (blockIdx.x & 127) << 4;
    const int d = dbase + g;
    const float A_dn = -expf(A_log[d * DS + n]);
    const float Dd = Dvec[d];
    float hs = 0.f;

    for (int c = 0; c < 16; ++c) {
        const int t0 = c * 64;
        // cooperative loads
#pragma unroll
        for (int k = 0; k < 8; ++k) {
            int idx = tid + k * 256;            // 64*32
            int i = idx >> 5, j = idx & 31;
            sBC[i][j] = xdbl[(size_t)(b * L_ + t0 + i) * 96 + 64 + j];
        }
#pragma unroll
        for (int k = 0; k < 4; ++k) {
            int idx = tid + k * 256;            // 64*16
            int i = idx >> 4, jj = idx & 15;
            size_t off = (size_t)(b * L_ + t0 + i) * DIN + dbase + jj;
            sdt[i][jj] = dtf[off];
            su[i][jj] = uc[off];
        }
        __syncthreads();
        // serial chain over 64 steps
        for (int i = 0; i < 64; ++i) {
            float dtv = sdt[i][g], uv = su[i][g];
            float Bv = sBC[i][n], Cv = sBC[i][16 + n];
            float dA = expf(dtv * A_dn);
            hs = fmaf(dA, hs, dtv * Bv * uv);
            float p = hs * Cv;
            p += __shfl_xor(p, 1);
            p += __shfl_xor(p, 2);
            p += __shfl_xor(p, 4);
            p += __shfl_xor(p, 8);
            if (n == 0) sy[i][g] = fmaf(uv, Dd, p);
        }
        __syncthreads();
        // write y back into uc (in place)
#pragma unroll
        for (int k = 0; k < 4; ++k) {
            int idx = tid + k * 256;
            int i = idx >> 4, jj = idx & 15;
            uc[(size_t)(b * L_ + t0 + i) * DIN + dbase + jj] = sy[i][jj];
        }
    }
}

// uc = y * silu(z), z = xz[...,DIN:2*DIN]
__global__ __launch_bounds__(256) void gate_k(float* __restrict__ uc,
                                              const float* __restrict__ xz)
{
    int idx = blockIdx.x * 256 + threadIdx.x;
    int d = idx & (DIN - 1);
    int nrow = idx >> 11;                      // b*L + t
    float z = xz[(size_t)nrow * (2 * DIN) + DIN + d];
    uc[idx] *= z * sigmoidf_(z);
}

__global__ __launch_bounds__(256) void addres_k(const float* __restrict__ h,
    const float* __restrict__ x, float* __restrict__ out)
{
    int i = blockIdx.x * 256 + threadIdx.x;
    out[i] = h[i] + x[i];
}

extern "C" void kernel_launch(void* const* d_in, const int* in_sizes, int n_in,
                              void* d_out, int out_size, void* d_ws, size_t ws_size,
                              hipStream_t stream)
{
    (void)in_sizes; (void)n_in; (void)out_size; (void)ws_size;
    const float* x      = (const float*)d_in[0];
    const float* W_in   = (const float*)d_in[1];
    const float* conv_w = (const float*)d_in[2];
    const float* conv_b = (const float*)d_in[3];
    const float* W_x    = (const float*)d_in[4];
    const float* W_dt   = (const float*)d_in[5];
    const float* b_dt   = (const float*)d_in[6];
    const float* A_log  = (const float*)d_in[7];
    const float* Dv     = (const float*)d_in[8];
    const float* W_out  = (const float*)d_in[9];
    float* out = (float*)d_out;

    float* ws   = (float*)d_ws;
    float* h    = ws;                               // B*L*DM      = 2,097,152
    float* xz   = h + (size_t)B_ * L_ * DM;         // B*L*2*DIN   = 8,388,608
    float* uc   = xz + (size_t)B_ * L_ * 2 * DIN;   // B*L*DIN     = 4,194,304
    float* xdbl = uc + (size_t)B_ * L_ * DIN;       // B*L*96      =   196,608
    float* dtf  = xdbl + (size_t)B_ * L_ * 96;      // B*L*DIN     = 4,194,304

    hipMemcpyAsync(h, x, sizeof(float) * B_ * L_ * DM, hipMemcpyDeviceToDevice, stream);

    const int M = B_ * L_;
    for (int layer = 0; layer < 2; ++layer) {
        // xz = h @ W_in^T   [M, 4096]
        gemm_bt<0><<<dim3(2 * DIN / 64, M / 64), 256, 0, stream>>>(
            h, W_in + (size_t)layer * 2 * DIN * DM, xz, nullptr, M, 2 * DIN, DM, DM, DM);
        // uc = silu(conv(u) + b)
        conv_silu_k<<<(B_ * L_ * DIN) / 256, 256, 0, stream>>>(
            xz, conv_w + (size_t)layer * DIN * 4, conv_b + (size_t)layer * DIN, uc);
        // xdbl = uc @ W_x^T  [M, 96]
        gemm_bt<0><<<dim3(2, M / 64), 256, 0, stream>>>(
            uc, W_x + (size_t)layer * 96 * DIN, xdbl, nullptr, M, 96, DIN, DIN, DIN);
        // dtf = softplus(xdbl[:, :64] @ W_dt^T + b_dt)  [M, 2048]
        gemm_bt<1><<<dim3(DIN / 64, M / 64), 256, 0, stream>>>(
            xdbl, W_dt + (size_t)layer * DIN * DTR, dtf, b_dt + (size_t)layer * DIN,
            M, DIN, DTR, 96, DTR);
        // selective scan (writes y into uc)
        scan_k<<<256, 256, 0, stream>>>(dtf, uc, xdbl,
            A_log + (size_t)layer * DIN * DS, Dv + (size_t)layer * DIN);
        // uc = y * silu(z)
        gate_k<<<(B_ * L_ * DIN) / 256, 256, 0, stream>>>(uc, xz);
        // h = uc @ W_out^T  [M, 1024]
        gemm_bt<0><<<dim3(DM / 64, M / 64), 256, 0, stream>>>(
            uc, W_out + (size_t)layer * DM * DIN, h, nullptr, M, DM, DIN, DIN, DIN);
    }
    addres_k<<<(B_ * L_ * DM) / 256, 256, 0, stream>>>(h, x, out);
}

// Round 3
// 616.832 us; speedup vs baseline: 3.5048x; 3.5048x over previous
//
#include <hip/hip_runtime.h>
#include <hip/hip_bf16.h>
#include <math.h>

#define B_ 2
#define L_ 1024
#define DM 1024
#define DIN 2048
#define DS 16
#define DTR 64

typedef __attribute__((ext_vector_type(8))) short bf16x8;
typedef __attribute__((ext_vector_type(4))) float f32x4;
typedef unsigned short ushort_t;
typedef unsigned int uint_t;

__device__ __forceinline__ float sigmoidf_(float x) { return 1.f / (1.f + __expf(-x)); }
__device__ __forceinline__ ushort_t f2b(float f) {
    uint_t b = __float_as_uint(f);
    return (ushort_t)((b + 0x7FFFu + ((b >> 16) & 1u)) >> 16);
}
__device__ __forceinline__ float b2f(ushort_t u) {
    return __uint_as_float(((uint_t)u) << 16);
}

// f32 -> bf16 (RTN) elementwise
__global__ __launch_bounds__(256) void f2b_k(const float* __restrict__ in,
                                             ushort_t* __restrict__ out, int n)
{
    int i = blockIdx.x * 256 + threadIdx.x;
    if (i < n) out[i] = f2b(in[i]);
}

// ---------------- MFMA GEMM: C[M,N] = A[M,K] * Bt[N,K]^T (bf16 in, f32 acc) ----
// EPI: 0 = f32 C; 1 = f32 C + bf16 Cb; 2 = softplus(C + bias[n]) f32; 3 = bf16 only;
//      4 = f32 C = acc + res
template<int EPI>
__global__ __launch_bounds__(256) void mgemm(const ushort_t* __restrict__ A,
    const ushort_t* __restrict__ Bt, float* __restrict__ Cf, ushort_t* __restrict__ Cb,
    const float* __restrict__ bias, const float* __restrict__ res,
    int M, int N, int K, int lda, int ldb)
{
    __shared__ ushort_t sA[128 * 32];
    __shared__ ushort_t sB[128 * 32];
    const int tid = threadIdx.x;
    const int lane = tid & 63, wv = tid >> 6;
    const int wm = wv >> 1, wn = wv & 1;
    const int m0 = blockIdx.y * 128, n0 = blockIdx.x * 128;
    const int sr = tid >> 2;            // 0..63
    const int sc = (tid & 3) * 8;       // 0,8,16,24
    f32x4 acc[4][4] = {};

    for (int k0 = 0; k0 < K; k0 += 32) {
#pragma unroll
        for (int j = 0; j < 2; ++j) {
            int ra = sr + j * 64;
            int ga = m0 + ra;
            __builtin_amdgcn_global_load_lds(
                (const uint_t*)(A + (size_t)ga * lda + k0 + sc),
                (uint_t*)(sA + ra * 32 + sc), 16, 0, 0);
            int gb = n0 + ra; if (gb >= N) gb = N - 1;   // clamp (N=96 case)
            __builtin_amdgcn_global_load_lds(
                (const uint_t*)(Bt + (size_t)gb * ldb + k0 + sc),
                (uint_t*)(sB + ra * 32 + sc), 16, 0, 0);
        }
        __syncthreads();
        bf16x8 af[4], bfr[4];
#pragma unroll
        for (int i = 0; i < 4; ++i) {
            af[i]  = *(const bf16x8*)(sA + (wm * 64 + i * 16 + (lane & 15)) * 32 + (lane >> 4) * 8);
            bfr[i] = *(const bf16x8*)(sB + (wn * 64 + i * 16 + (lane & 15)) * 32 + (lane >> 4) * 8);
        }
#pragma unroll
        for (int i = 0; i < 4; ++i)
#pragma unroll
            for (int jj = 0; jj < 4; ++jj)
                acc[i][jj] = __builtin_amdgcn_mfma_f32_16x16x32_bf16(af[i], bfr[jj], acc[i][jj], 0, 0, 0);
        __syncthreads();
    }

    const int cr = (lane >> 4) * 4, cc = lane & 15;
#pragma unroll
    for (int i = 0; i < 4; ++i) {
        int mrow = m0 + wm * 64 + i * 16 + cr;
#pragma unroll
        for (int jj = 0; jj < 4; ++jj) {
            int ncol = n0 + wn * 64 + jj * 16 + cc;
            if (ncol < N) {
#pragma unroll
                for (int r = 0; r < 4; ++r) {
                    float v = acc[i][jj][r];
                    size_t off = (size_t)(mrow + r) * N + ncol;
                    if (EPI == 0) { Cf[off] = v; }
                    else if (EPI == 1) { Cf[off] = v; Cb[off] = f2b(v); }
                    else if (EPI == 2) {
                        float s = v + bias[ncol];
                        Cf[off] = (s > 20.f) ? s : log1pf(expf(s));
                    }
                    else if (EPI == 3) { Cb[off] = f2b(v); }
                    else { Cf[off] = v + res[off]; }
                }
            }
        }
    }
}

// conv + silu: reads bf16 xz (u half), writes f32 uc and bf16 ucb
__global__ __launch_bounds__(256) void conv_silu_k(const ushort_t* __restrict__ xzb,
    const float* __restrict__ cw, const float* __restrict__ cb,
    float* __restrict__ uc, ushort_t* __restrict__ ucb)
{
    int idx = blockIdx.x * 256 + threadIdx.x;   // over B*L*DIN
    int d = idx & (DIN - 1);
    int t = (idx >> 11) & (L_ - 1);
    int b = idx >> 21;
    const ushort_t* base = xzb + (size_t)b * L_ * (2 * DIN) + d;
    float acc = cb[d];
#pragma unroll
    for (int j = 0; j < 4; ++j) {
        int tt = t - 3 + j;
        if (tt >= 0) acc = fmaf(cw[d * 4 + j], b2f(base[(size_t)tt * (2 * DIN)]), acc);
    }
    float v = acc * sigmoidf_(acc);
    uc[idx] = v;
    ucb[idx] = f2b(v);
}

// ---------------- selective scan, deferred reduction -------------------------
// 16 channels x 16 states per block; chain = 1 fma/step; p-values to LDS;
// per-chunk reduce over n; gate y*silu(z) fused; writes bf16 ucb.
__global__ __launch_bounds__(256) void scan2_k(const float* __restrict__ dtf,
    const float* __restrict__ uc, const float* __restrict__ xdbl,
    const ushort_t* __restrict__ xzb, const float* __restrict__ A_log,
    const float* __restrict__ Dvec, ushort_t* __restrict__ ucb)
{
    __shared__ float sBC[64 * 32];       // [t][32] B then C
    __shared__ float sdt[64 * 16];       // [t][g]
    __shared__ float suT[16 * 65];       // [g][t] padded
    __shared__ float sy[64 * 257];       // [t][tid] padded, p-values
    __shared__ float sy3[64 * 17];       // [t][g] padded, reduced y (pre-gate)
    __shared__ float sD[16];
    const int tid = threadIdx.x;
    const int lane = tid & 63, wave = tid >> 6;
    const int g = tid >> 4, n = tid & 15;
    const int b = blockIdx.x >> 7;
    const int dbase = (blockIdx.x & 127) << 4;
    const int d = dbase + g;
    const float A_dn = -__expf(A_log[(size_t)d * DS + n]);
    if (tid < 16) sD[tid] = Dvec[dbase + tid];
    float hs = 0.f;

    float rBC[8], rdt[4], ru[4];
    // prefetch chunk 0
    {
        const int t0 = 0;
#pragma unroll
        for (int j = 0; j < 8; ++j) {
            int idx = tid + j * 256; int i = idx >> 5, jj = idx & 31;
            rBC[j] = xdbl[(size_t)(b * L_ + t0 + i) * 96 + 64 + jj];
        }
#pragma unroll
        for (int j = 0; j < 4; ++j) {
            int idx = tid + j * 256; int i = idx >> 4, jj = idx & 15;
            size_t off = (size_t)(b * L_ + t0 + i) * DIN + dbase + jj;
            rdt[j] = dtf[off];
            ru[j] = uc[off];
        }
    }

    for (int c = 0; c < 16; ++c) {
        const int t0 = c * 64;
        __syncthreads();                    // LDS free for overwrite
#pragma unroll
        for (int j = 0; j < 8; ++j) {
            int idx = tid + j * 256;
            sBC[idx] = rBC[j];
        }
#pragma unroll
        for (int j = 0; j < 4; ++j) {
            int idx = tid + j * 256; int i = idx >> 4, jj = idx & 15;
            sdt[idx] = rdt[j];
            suT[jj * 65 + i] = ru[j];
        }
        __syncthreads();
        if (c < 15) {                       // prefetch next chunk into regs
            const int t1 = t0 + 64;
#pragma unroll
            for (int j = 0; j < 8; ++j) {
                int idx = tid + j * 256; int i = idx >> 5, jj = idx & 31;
                rBC[j] = xdbl[(size_t)(b * L_ + t1 + i) * 96 + 64 + jj];
            }
#pragma unroll
            for (int j = 0; j < 4; ++j) {
                int idx = tid + j * 256; int i = idx >> 4, jj = idx & 15;
                size_t off = (size_t)(b * L_ + t1 + i) * DIN + dbase + jj;
                rdt[j] = dtf[off];
                ru[j] = uc[off];
            }
        }
        // serial phase: chain is only hs = fma(dA, hs, dBu)
#pragma unroll 8
        for (int i = 0; i < 64; ++i) {
            float dtv = sdt[i * 16 + g];
            float uv  = suT[g * 65 + i];
            float Bv  = sBC[i * 32 + n];
            float Cv  = sBC[i * 32 + 16 + n];
            float dA  = __expf(dtv * A_dn);
            hs = fmaf(dA, hs, dtv * Bv * uv);
            sy[i * 257 + tid] = hs * Cv;
        }
        __syncthreads();
        // reduce over n: pair (i=lane, g2=wave+4k)
#pragma unroll
        for (int k = 0; k < 4; ++k) {
            int g2 = wave + 4 * k;
            float sum = 0.f;
#pragma unroll
            for (int nn = 0; nn < 16; ++nn) sum += sy[lane * 257 + g2 * 16 + nn];
            float uv = suT[g2 * 65 + lane];
            sy3[lane * 17 + g2] = fmaf(uv, sD[g2], sum);
        }
        __syncthreads();
        // gated coalesced store
#pragma unroll
        for (int k = 0; k < 4; ++k) {
            int idx = tid + k * 256; int row = idx >> 4, col = idx & 15;
            float y = sy3[row * 17 + col];
            float z = b2f(xzb[(size_t)(b * L_ + t0 + row) * (2 * DIN) + DIN + dbase + col]);
            y *= z * sigmoidf_(z);
            ucb[(size_t)(b * L_ + t0 + row) * DIN + dbase + col] = f2b(y);
        }
    }
}

extern "C" void kernel_launch(void* const* d_in, const int* in_sizes, int n_in,
                              void* d_out, int out_size, void* d_ws, size_t ws_size,
                              hipStream_t stream)
{
    (void)in_sizes; (void)n_in; (void)out_size; (void)ws_size;
    const float* x      = (const float*)d_in[0];
    const float* W_in   = (const float*)d_in[1];
    const float* conv_w = (const float*)d_in[2];
    const float* conv_b = (const float*)d_in[3];
    const float* W_x    = (const float*)d_in[4];
    const float* W_dt   = (const float*)d_in[5];
    const float* b_dt   = (const float*)d_in[6];
    const float* A_log  = (const float*)d_in[7];
    const float* Dv     = (const float*)d_in[8];
    const float* W_out  = (const float*)d_in[9];
    float* out = (float*)d_out;

    // workspace layout
    float* uc      = (float*)d_ws;                       // 4,194,304 f32
    float* xdbl    = uc + 4194304;                       //   196,608 f32
    float* dtf     = xdbl + 196608;                      // 4,194,304 f32
    ushort_t* xzb  = (ushort_t*)(dtf + 4194304);         // 8,388,608 u16
    ushort_t* ucb  = xzb + 8388608;                      // 4,194,304
    ushort_t* xdblb= ucb + 4194304;                      //   196,608
    ushort_t* xb   = xdblb + 196608;                     // 2,097,152 (x bf16, reused as h bf16)
    ushort_t* wib  = xb + 2097152;                       // 8,388,608
    ushort_t* wxb  = wib + 8388608;                      //   393,216
    ushort_t* wdb  = wxb + 393216;                       //   262,144
    ushort_t* wob  = wdb + 262144;                       // 4,194,304

    const int M = B_ * L_;
    // converts
    f2b_k<<<2097152 / 256, 256, 0, stream>>>(x, xb, 2097152);
    f2b_k<<<8388608 / 256, 256, 0, stream>>>(W_in, wib, 8388608);
    f2b_k<<<(393216 + 255) / 256, 256, 0, stream>>>(W_x, wxb, 393216);
    f2b_k<<<(262144 + 255) / 256, 256, 0, stream>>>(W_dt, wdb, 262144);
    f2b_k<<<4194304 / 256, 256, 0, stream>>>(W_out, wob, 4194304);

    for (int layer = 0; layer < 2; ++layer) {
        // xzb = bf16( h @ W_in^T )  [M, 4096]
        mgemm<3><<<dim3(4096 / 128, M / 128), 256, 0, stream>>>(
            xb, wib + (size_t)layer * 4194304, nullptr, xzb, nullptr, nullptr,
            M, 2 * DIN, DM, DM, DM);
        // uc/ucb = silu(conv(u) + b)
        conv_silu_k<<<(B_ * L_ * DIN) / 256, 256, 0, stream>>>(
            xzb, conv_w + (size_t)layer * DIN * 4, conv_b + (size_t)layer * DIN, uc, ucb);
        // xdbl (f32 + bf16) = uc @ W_x^T  [M, 96]
        mgemm<1><<<dim3(1, M / 128), 256, 0, stream>>>(
            ucb, wxb + (size_t)layer * 196608, xdbl, xdblb, nullptr, nullptr,
            M, 96, DIN, DIN, DIN);
        // dtf = softplus(xdblb[:, :64] @ W_dt^T + b_dt)  [M, 2048]
        mgemm<2><<<dim3(2048 / 128, M / 128), 256, 0, stream>>>(
            xdblb, wdb + (size_t)layer * 131072, dtf, nullptr,
            b_dt + (size_t)layer * DIN, nullptr, M, DIN, DTR, 96, DTR);
        // selective scan + gate -> ucb (bf16)
        scan2_k<<<256, 256, 0, stream>>>(dtf, uc, xdbl, xzb,
            A_log + (size_t)layer * DIN * DS, Dv + (size_t)layer * DIN, ucb);
        // out-proj: layer0 -> xb (bf16 h); layer1 -> out = acc + x
        if (layer == 0)
            mgemm<3><<<dim3(1024 / 128, M / 128), 256, 0, stream>>>(
                ucb, wob + (size_t)layer * 2097152, nullptr, xb, nullptr, nullptr,
                M, DM, DIN, DIN, DIN);
        else
            mgemm<4><<<dim3(1024 / 128, M / 128), 256, 0, stream>>>(
                ucb, wob + (size_t)layer * 2097152, out, nullptr, nullptr, x,
                M, DM, DIN, DIN, DIN);
    }
}